// Round 12
// baseline (175.897 us; speedup 1.0000x reference)
//
#include <hip/hip_runtime.h>
#include <hip/hip_bf16.h>

#define S_NODES 8192
#define P_PATHS 16
#define K_EP    16
#define D_DIM   128
#define H_DIM   64

typedef __bf16 bf16x8_t __attribute__((ext_vector_type(8)));
typedef float  f32x4_t  __attribute__((ext_vector_type(4)));
typedef unsigned int u32x4 __attribute__((ext_vector_type(4)));

#define AGGF_STRIDE  132   // floats
#define AGGBF_STRIDE 136   // bf16; rows 272B, 16B-aligned for b128 A-frag reads

// ---- fused prep: out=0, entity fp32->bf16 (+1 zero pad row), W1 -> W1^T bf16 ----
__global__ __launch_bounds__(256)
void prep_fused_kernel(const float* __restrict__ ent, const float* __restrict__ W1,
                       __bf16* __restrict__ entbf, __bf16* __restrict__ w1t,
                       float4* __restrict__ out4, int n4, int o4)
{
    const int i = blockIdx.x * 256 + threadIdx.x;
    if (i < n4) {
        float4 v = ((const float4*)ent)[i];
        union { __bf16 h[4]; uint2 u; } pk;
        pk.h[0] = (__bf16)v.x; pk.h[1] = (__bf16)v.y;
        pk.h[2] = (__bf16)v.z; pk.h[3] = (__bf16)v.w;
        ((uint2*)entbf)[i] = pk.u;
    }
    if (i < 32)  // zero pad row at entity index N (256 B)
        ((uint2*)entbf)[n4 + i] = make_uint2(0u, 0u);
    if (i < o4) out4[i] = make_float4(0.f, 0.f, 0.f, 0.f);
    if (i < D_DIM * H_DIM) {
        const int n = i >> 7, d = i & 127;
        w1t[i] = (__bf16)W1[d * H_DIM + n];
    }
}

// ---- fallback-path prep ----
__global__ __launch_bounds__(256)
void prep_w1_kernel(const float* __restrict__ W1, __bf16* __restrict__ w1t)
{
    const int idx = blockIdx.x * 256 + threadIdx.x;   // 32 x 256 = 8192
    const int n = idx >> 7, d = idx & 127;
    w1t[idx] = (__bf16)W1[d * H_DIM + n];
}

// unpack a 16B bf16x8 chunk into two fp32 float4 accumulators
__device__ __forceinline__ void acc_row4(float4& lo, float4& hi, u32x4 r)
{
    lo.x += __uint_as_float(r[0] << 16); lo.y += __uint_as_float(r[0] & 0xffff0000u);
    lo.z += __uint_as_float(r[1] << 16); lo.w += __uint_as_float(r[1] & 0xffff0000u);
    hi.x += __uint_as_float(r[2] << 16); hi.y += __uint_as_float(r[2] & 0xffff0000u);
    hi.z += __uint_as_float(r[3] << 16); hi.w += __uint_as_float(r[3] & 0xffff0000u);
}

// full quarter-merge: after xor16 + xor32 every lane holds the sum over all 4 quarters
__device__ __forceinline__ void merge_quarters(float4& v)
{
    v.x += __shfl_xor(v.x, 16); v.y += __shfl_xor(v.y, 16);
    v.z += __shfl_xor(v.z, 16); v.w += __shfl_xor(v.w, 16);
    v.x += __shfl_xor(v.x, 32); v.y += __shfl_xor(v.y, 32);
    v.z += __shfl_xor(v.z, 32); v.w += __shfl_xor(v.w, 32);
}

// bf16 launch: 512 threads (8 waves x 2 paths); fallback launch: 256 threads (4 waves x 4 paths)
template<bool USE_BF16>
__global__ __launch_bounds__(512, 4)   // VGPR cap 128; forced-ILP batch needs ~80
void PathGuidedAggregator_kernel(const float*  __restrict__ ent,
                                 const __bf16* __restrict__ entbf,  // bf16 table + zero pad row (ws)
                                 const float*  __restrict__ b1,
                                 const float*  __restrict__ W2,
                                 const float*  __restrict__ b2,
                                 const int*    __restrict__ sids,
                                 const int*    __restrict__ eids,
                                 const void*   __restrict__ emask,
                                 const __bf16* __restrict__ w1t,    // [H][D] bf16 (ws)
                                 float*        __restrict__ out,
                                 int nent)                          // pad row index
{
    __shared__ float  aggf [P_PATHS][AGGF_STRIDE];   // fp32 agg (epilogue w*agg)
    __shared__ __bf16 aggbf[P_PATHS][AGGBF_STRIDE];  // bf16 agg (MFMA A operand)
    __shared__ int    cnts[P_PATHS];
    __shared__ int    comp[4][4][K_EP];              // fallback path only

    const int s    = blockIdx.x;
    const int tid  = threadIdx.x;
    const int wave = tid >> 6;
    const int lane = tid & 63;

    // ---- runtime detection of bool-mask storage: int32 / uint8 / float32 ----
    const unsigned int* mw = (const unsigned int*)emask;
    unsigned int probe = mw[lane];
    const bool floatMask = (__ballot(probe == 0x3F800000u) != 0ULL);
    const bool byteMask  = !floatMask && (__ballot(probe > 1u) != 0ULL);

    if constexpr (USE_BF16) {
        // ---- 8 waves x 2 paths; the 8-load batch is FORCED via inline asm:
        // 8 back-to-back global_load_dwordx4 + one s_waitcnt vmcnt(0) -> exactly one
        // gather latency window per wave, un-reorderable, un-spillable.
        const int base = (s * P_PATHS + wave * 2) * K_EP;   // 32 endpoint slots
        int idv = 0, mk = 0;
        if (lane < 32) {
            idv = eids[base + lane];
            if (floatMask)     mk = (((const float*)emask)[base + lane] != 0.0f);
            else if (byteMask) mk = ((const unsigned char*)emask)[base + lane];
            else               mk = ((const int*)emask)[base + lane];
        }
        const unsigned int bits = (unsigned int)__ballot(mk != 0);   // lanes>=32 contribute 0
        const int c0 = __popc(bits & 0xFFFFu);
        const int c1 = __popc(bits >> 16);
        if (lane == 0) cnts[wave * 2]     = c0;
        if (lane == 1) cnts[wave * 2 + 1] = c1;

        const int idm = mk ? idv : nent;             // invalid slots -> zero pad row
        const int rho = (lane >> 4) & 3;             // quarter owns slots 4u+rho
        const int c16 = lane & 15;
        const uint4* __restrict__ entb = (const uint4*)entbf;

        const uint4* a0 = entb + (size_t)__shfl(idm,      rho) * 16 + c16;  // path0
        const uint4* a1 = entb + (size_t)__shfl(idm,  4 + rho) * 16 + c16;
        const uint4* a2 = entb + (size_t)__shfl(idm,  8 + rho) * 16 + c16;
        const uint4* a3 = entb + (size_t)__shfl(idm, 12 + rho) * 16 + c16;
        const uint4* a4 = entb + (size_t)__shfl(idm, 16 + rho) * 16 + c16;  // path1
        const uint4* a5 = entb + (size_t)__shfl(idm, 20 + rho) * 16 + c16;
        const uint4* a6 = entb + (size_t)__shfl(idm, 24 + rho) * 16 + c16;
        const uint4* a7 = entb + (size_t)__shfl(idm, 28 + rho) * 16 + c16;

        u32x4 r0, r1, r2, r3, r4, r5, r6, r7;
        asm volatile(
            "global_load_dwordx4 %0, %8, off\n\t"
            "global_load_dwordx4 %1, %9, off\n\t"
            "global_load_dwordx4 %2, %10, off\n\t"
            "global_load_dwordx4 %3, %11, off\n\t"
            "global_load_dwordx4 %4, %12, off\n\t"
            "global_load_dwordx4 %5, %13, off\n\t"
            "global_load_dwordx4 %6, %14, off\n\t"
            "global_load_dwordx4 %7, %15, off\n\t"
            "s_waitcnt vmcnt(0)"
            : "=&v"(r0), "=&v"(r1), "=&v"(r2), "=&v"(r3),
              "=&v"(r4), "=&v"(r5), "=&v"(r6), "=&v"(r7)
            : "v"(a0), "v"(a1), "v"(a2), "v"(a3),
              "v"(a4), "v"(a5), "v"(a6), "v"(a7)
            : "memory");

        // path 0: consume r0-r3
        float4 lo = {0.f,0.f,0.f,0.f}, hi = lo;
        acc_row4(lo, hi, r0); acc_row4(lo, hi, r1);
        acc_row4(lo, hi, r2); acc_row4(lo, hi, r3);
        merge_quarters(lo); merge_quarters(hi);
        {
            const float invq = 1.0f / (float)(c0 > 1 ? c0 : 1);
            if (rho == 0) {      // lanes 0-15 store path 2*wave
                float4 L = lo, H = hi;
                L.x *= invq; L.y *= invq; L.z *= invq; L.w *= invq;
                H.x *= invq; H.y *= invq; H.z *= invq; H.w *= invq;
                const int pw = wave * 2;
                *(float4*)&aggf[pw][c16 * 8]     = L;
                *(float4*)&aggf[pw][c16 * 8 + 4] = H;
                union { __bf16 hh[8]; uint4 u4; } pk;
                pk.hh[0] = (__bf16)L.x; pk.hh[1] = (__bf16)L.y;
                pk.hh[2] = (__bf16)L.z; pk.hh[3] = (__bf16)L.w;
                pk.hh[4] = (__bf16)H.x; pk.hh[5] = (__bf16)H.y;
                pk.hh[6] = (__bf16)H.z; pk.hh[7] = (__bf16)H.w;
                *(uint4*)&aggbf[pw][c16 * 8] = pk.u4;
            }
        }
        // path 1: consume r4-r7
        float4 lo1 = {0.f,0.f,0.f,0.f}, hi1 = lo1;
        acc_row4(lo1, hi1, r4); acc_row4(lo1, hi1, r5);
        acc_row4(lo1, hi1, r6); acc_row4(lo1, hi1, r7);
        merge_quarters(lo1); merge_quarters(hi1);
        {
            const float invq = 1.0f / (float)(c1 > 1 ? c1 : 1);
            if (rho == 1) {      // lanes 16-31 store path 2*wave+1
                float4 L = lo1, H = hi1;
                L.x *= invq; L.y *= invq; L.z *= invq; L.w *= invq;
                H.x *= invq; H.y *= invq; H.z *= invq; H.w *= invq;
                const int pw = wave * 2 + 1;
                *(float4*)&aggf[pw][c16 * 8]     = L;
                *(float4*)&aggf[pw][c16 * 8 + 4] = H;
                union { __bf16 hh[8]; uint4 u4; } pk;
                pk.hh[0] = (__bf16)L.x; pk.hh[1] = (__bf16)L.y;
                pk.hh[2] = (__bf16)L.z; pk.hh[3] = (__bf16)L.w;
                pk.hh[4] = (__bf16)H.x; pk.hh[5] = (__bf16)H.y;
                pk.hh[6] = (__bf16)H.z; pk.hh[7] = (__bf16)H.w;
                *(uint4*)&aggbf[pw][c16 * 8] = pk.u4;
            }
        }
    } else {
        // ---- fp32 fallback (round-4 structure, launched with 256 threads) ----
        const int base = (s * P_PATHS + wave * 4) * K_EP;
        const int idv  = eids[base + lane];
        int mk;
        if (floatMask)     mk = (((const float*)emask)[base + lane] != 0.0f);
        else if (byteMask) mk = ((const unsigned char*)emask)[base + lane];
        else               mk = ((const int*)emask)[base + lane];
        const unsigned long long bits_all = __ballot(mk != 0);
        const int k16  = lane & 15;
        const int pgrp = lane >> 4;
        if (lane < 4) cnts[wave * 4 + lane] = __popc((unsigned int)((bits_all >> (16 * lane)) & 0xFFFFu));
        const int c0 = __popc((unsigned int)( bits_all        & 0xFFFFu));
        const int c1 = __popc((unsigned int)((bits_all >> 16) & 0xFFFFu));
        const int c2 = __popc((unsigned int)((bits_all >> 32) & 0xFFFFu));
        const int c3 = __popc((unsigned int)((bits_all >> 48) & 0xFFFFu));
        const unsigned int bits_p = (unsigned int)((bits_all >> (16 * pgrp)) & 0xFFFFu);
        comp[wave][pgrp][k16] = 0;
        if (mk) comp[wave][pgrp][__popc(bits_p & ((1u << k16) - 1u))] = idv;
        const int half = lane >> 5;
        const int col  = lane & 31;
        const float4* __restrict__ entc = (const float4*)ent + col;
        float4 acc0 = {0.f,0.f,0.f,0.f}, acc1 = acc0, acc2 = acc0, acc3 = acc0;
        #pragma unroll
        for (int u = 0; u < 8; ++u) {
            const int slot = 2 * u + half;
            const int id0 = comp[wave][0][slot];
            const int id1 = comp[wave][1][slot];
            const int id2 = comp[wave][2][slot];
            const int id3 = comp[wave][3][slot];
            if (slot < c0) { float4 v = entc[(size_t)id0 << 5]; acc0.x += v.x; acc0.y += v.y; acc0.z += v.z; acc0.w += v.w; }
            if (slot < c1) { float4 v = entc[(size_t)id1 << 5]; acc1.x += v.x; acc1.y += v.y; acc1.z += v.z; acc1.w += v.w; }
            if (slot < c2) { float4 v = entc[(size_t)id2 << 5]; acc2.x += v.x; acc2.y += v.y; acc2.z += v.z; acc2.w += v.w; }
            if (slot < c3) { float4 v = entc[(size_t)id3 << 5]; acc3.x += v.x; acc3.y += v.y; acc3.z += v.z; acc3.w += v.w; }
        }
        #pragma unroll
        for (int i = 0; i < 4; ++i) {
            float4 a = (i == 0) ? acc0 : (i == 1) ? acc1 : (i == 2) ? acc2 : acc3;
            const int cnt = (i == 0) ? c0 : (i == 1) ? c1 : (i == 2) ? c2 : c3;
            a.x += __shfl_xor(a.x, 32); a.y += __shfl_xor(a.y, 32);
            a.z += __shfl_xor(a.z, 32); a.w += __shfl_xor(a.w, 32);
            const float inv = 1.0f / (float)(cnt > 1 ? cnt : 1);
            a.x *= inv; a.y *= inv; a.z *= inv; a.w *= inv;
            if (half == 0) {
                const int p = wave * 4 + i;
                *(float4*)&aggf[p][col * 4] = a;
                union { __bf16 h[4]; uint2 u2; } pk;
                pk.h[0] = (__bf16)a.x; pk.h[1] = (__bf16)a.y;
                pk.h[2] = (__bf16)a.z; pk.h[3] = (__bf16)a.w;
                *(uint2*)&aggbf[p][col * 4] = pk.u2;
            }
        }
    }
    __syncthreads();

    if (wave != 0) return;

    // ---- MLP for all 16 paths via MFMA (wave 0) ----
    const int m    = lane & 15;
    const int quad = lane >> 4;

    bf16x8_t afr[4];
    #pragma unroll
    for (int st = 0; st < 4; ++st)
        afr[st] = *(const bf16x8_t*)&aggbf[m][st * 32 + quad * 8];

    float xp[4] = {0.f, 0.f, 0.f, 0.f};
    #pragma unroll
    for (int t = 0; t < 4; ++t) {
        const int n = t * 16 + m;
        const float b1v = b1[n];
        f32x4_t acc = {b1v, b1v, b1v, b1v};
        const __bf16* bp = w1t + n * D_DIM + quad * 8;
        #pragma unroll
        for (int st = 0; st < 4; ++st) {
            bf16x8_t bfr = *(const bf16x8_t*)(bp + st * 32);
            acc = __builtin_amdgcn_mfma_f32_16x16x32_bf16(afr[st], bfr, acc, 0, 0, 0);
        }
        const float w2v = W2[n];
        #pragma unroll
        for (int r = 0; r < 4; ++r) {
            float h = acc[r] > 0.f ? acc[r] : 0.f;
            xp[r] += h * w2v;
        }
    }
    #pragma unroll
    for (int off = 1; off < 16; off <<= 1) {
        #pragma unroll
        for (int r = 0; r < 4; ++r) xp[r] += __shfl_xor(xp[r], off);
    }

    int myc[4]; int localv = 0;
    #pragma unroll
    for (int r = 0; r < 4; ++r) { myc[r] = cnts[quad * 4 + r]; localv += (myc[r] > 0); }
    int nv = localv + __shfl_xor(localv, 16);
    nv += __shfl_xor(nv, 32);
    const float invnv = 1.0f / (float)(nv > 1 ? nv : 1);
    const float b2v = b2[0];

    float wv[4];
    #pragma unroll
    for (int r = 0; r < 4; ++r) {
        float x = xp[r] + b2v;
        float w = 1.0f / (1.0f + __expf(-x));
        wv[r] = (myc[r] > 0) ? w * invnv : 0.f;
    }

    float fx = 0.f, fy = 0.f;
    #pragma unroll
    for (int p = 0; p < P_PATHS; ++p) {
        float wp = __shfl(wv[p & 3], (p >> 2) << 4);
        float2 a = *(const float2*)&aggf[p][2 * lane];
        fx += wp * a.x; fy += wp * a.y;
    }
    const int row = sids[s];
    *(float2*)&out[(size_t)row * D_DIM + 2 * lane] = make_float2(fx, fy);
}

extern "C" void kernel_launch(void* const* d_in, const int* in_sizes, int n_in,
                              void* d_out, int out_size, void* d_ws, size_t ws_size,
                              hipStream_t stream)
{
    const float* ent  = (const float*)d_in[0];
    const float* W1   = (const float*)d_in[1];
    const float* b1   = (const float*)d_in[2];
    const float* W2   = (const float*)d_in[3];
    const float* b2   = (const float*)d_in[4];
    const int*   sids = (const int*)d_in[5];
    const int*   eids = (const int*)d_in[6];
    const void*  emsk = (const void*)d_in[7];
    float* out = (float*)d_out;

    const int ND   = in_sizes[0];                     // N*D elements of entity table
    const int nent = ND / D_DIM;                      // N (pad row index)
    __bf16* w1t_ws = (__bf16*)d_ws;                   // 16 KB
    __bf16* entbf  = (__bf16*)((char*)d_ws + 16384);  // 2*(ND + D) bytes (incl. pad row)
    const bool useBf16 = (ws_size >= 16384 + ((size_t)ND + D_DIM) * 2)
                         && ((ND & 3) == 0) && ((out_size & 3) == 0);

    if (useBf16) {
        const int n4 = ND >> 2, o4 = out_size >> 2;
        const int mx = n4 > o4 ? n4 : o4;
        prep_fused_kernel<<<(mx + 255) / 256, 256, 0, stream>>>(ent, W1, entbf, w1t_ws,
                                                                (float4*)out, n4, o4);
        PathGuidedAggregator_kernel<true><<<S_NODES, 512, 0, stream>>>(
            ent, (const __bf16*)entbf, b1, W2, b2, sids, eids, emsk,
            (const __bf16*)w1t_ws, out, nent);
    } else {
        hipMemsetAsync(d_out, 0, (size_t)out_size * sizeof(float), stream);
        prep_w1_kernel<<<32, 256, 0, stream>>>(W1, w1t_ws);
        PathGuidedAggregator_kernel<false><<<S_NODES, 256, 0, stream>>>(
            ent, (const __bf16*)entbf, b1, W2, b2, sids, eids, emsk,
            (const __bf16*)w1t_ws, out, nent);
    }
}

// Round 13
// 168.010 us; speedup vs baseline: 1.0469x; 1.0469x over previous
//
#include <hip/hip_runtime.h>
#include <hip/hip_bf16.h>

#define S_NODES 8192
#define P_PATHS 16
#define K_EP    16
#define D_DIM   128
#define H_DIM   64

typedef __bf16 bf16x8_t __attribute__((ext_vector_type(8)));
typedef float  f32x4_t  __attribute__((ext_vector_type(4)));

// LDS strides (elements per row), hot accesses <=2-way bank aliased (free):
#define AGGF_STRIDE  132   // floats
#define AGGBF_STRIDE 136   // bf16; rows 272B, 16B-aligned for b128 A-frag reads

// ---- fused prep: out=0, entity fp32->bf16 (+1 zero pad row), W1 -> W1^T bf16 ----
__global__ __launch_bounds__(256)
void prep_fused_kernel(const float* __restrict__ ent, const float* __restrict__ W1,
                       __bf16* __restrict__ entbf, __bf16* __restrict__ w1t,
                       float4* __restrict__ out4, int n4, int o4)
{
    const int i = blockIdx.x * 256 + threadIdx.x;
    if (i < n4) {
        float4 v = ((const float4*)ent)[i];
        union { __bf16 h[4]; uint2 u; } pk;
        pk.h[0] = (__bf16)v.x; pk.h[1] = (__bf16)v.y;
        pk.h[2] = (__bf16)v.z; pk.h[3] = (__bf16)v.w;
        ((uint2*)entbf)[i] = pk.u;
    }
    if (i < 32)  // zero pad row at entity index N (256 B)
        ((uint2*)entbf)[n4 + i] = make_uint2(0u, 0u);
    if (i < o4) out4[i] = make_float4(0.f, 0.f, 0.f, 0.f);
    if (i < D_DIM * H_DIM) {
        const int n = i >> 7, d = i & 127;
        w1t[i] = (__bf16)W1[d * H_DIM + n];
    }
}

// ---- fallback-path prep ----
__global__ __launch_bounds__(256)
void prep_w1_kernel(const float* __restrict__ W1, __bf16* __restrict__ w1t)
{
    const int idx = blockIdx.x * 256 + threadIdx.x;   // 32 x 256 = 8192
    const int n = idx >> 7, d = idx & 127;
    w1t[idx] = (__bf16)W1[d * H_DIM + n];
}

// unpack a 16B bf16x8 chunk into two fp32 float4 accumulators
__device__ __forceinline__ void acc_row(float4& lo, float4& hi, uint4 r)
{
    lo.x += __uint_as_float(r.x << 16); lo.y += __uint_as_float(r.x & 0xffff0000u);
    lo.z += __uint_as_float(r.y << 16); lo.w += __uint_as_float(r.y & 0xffff0000u);
    hi.x += __uint_as_float(r.z << 16); hi.y += __uint_as_float(r.z & 0xffff0000u);
    hi.z += __uint_as_float(r.w << 16); hi.w += __uint_as_float(r.w & 0xffff0000u);
}

__device__ __forceinline__ void merge_quarters(float4& v)
{
    v.x += __shfl_xor(v.x, 16); v.y += __shfl_xor(v.y, 16);
    v.z += __shfl_xor(v.z, 16); v.w += __shfl_xor(v.w, 16);
    v.x += __shfl_xor(v.x, 32); v.y += __shfl_xor(v.y, 32);
    v.z += __shfl_xor(v.z, 32); v.w += __shfl_xor(v.w, 32);
}

template<bool USE_BF16>
__global__ __launch_bounds__(256, 5)   // R8 champion config: ~48 VGPR, no spill, 41% occ
void PathGuidedAggregator_kernel(const float*  __restrict__ ent,
                                 const __bf16* __restrict__ entbf,  // bf16 table + zero pad row (ws)
                                 const float*  __restrict__ b1,
                                 const float*  __restrict__ W2,
                                 const float*  __restrict__ b2,
                                 const int*    __restrict__ sids,
                                 const int*    __restrict__ eids,
                                 const void*   __restrict__ emask,
                                 const __bf16* __restrict__ w1t,    // [H][D] bf16 (ws)
                                 float*        __restrict__ out,
                                 int nent)                          // pad row index
{
    __shared__ float  aggf [P_PATHS][AGGF_STRIDE];   // fp32 agg (epilogue w*agg)
    __shared__ __bf16 aggbf[P_PATHS][AGGBF_STRIDE];  // bf16 agg (MFMA A operand)
    __shared__ int    cnts[P_PATHS];
    __shared__ int    comp[4][4][K_EP];              // fallback + bf16 id staging

    const int s    = blockIdx.x;
    const int tid  = threadIdx.x;
    const int wave = tid >> 6;
    const int lane = tid & 63;

    // ---- runtime detection of bool-mask storage: int32 / uint8 / float32 ----
    const unsigned int* mw = (const unsigned int*)emask;
    unsigned int probe = mw[lane];
    const bool floatMask = (__ballot(probe == 0x3F800000u) != 0ULL);
    const bool byteMask  = !floatMask && (__ballot(probe > 1u) != 0ULL);

    // ---- one coalesced 64-lane load covers ids+mask for this wave's 4 paths ----
    const int base = (s * P_PATHS + wave * 4) * K_EP;
    const int idv  = eids[base + lane];
    int mk;
    if (floatMask)     mk = (((const float*)emask)[base + lane] != 0.0f);
    else if (byteMask) mk = ((const unsigned char*)emask)[base + lane];
    else               mk = ((const int*)emask)[base + lane];
    const unsigned long long bits_all = __ballot(mk != 0);

    const int k16  = lane & 15;
    const int pgrp = lane >> 4;

    // compact valid ids; pad slots point at the zero row (bf16 path) so loads need no guards
    const unsigned int bits_p = (unsigned int)((bits_all >> (16 * pgrp)) & 0xFFFFu);
    comp[wave][pgrp][k16] = USE_BF16 ? nent : 0;
    if (mk) comp[wave][pgrp][__popc(bits_p & ((1u << k16) - 1u))] = idv;
    if (lane < 4) cnts[wave * 4 + lane] = __popc((unsigned int)((bits_all >> (16 * lane)) & 0xFFFFu));

    const int c0 = __popc((unsigned int)( bits_all        & 0xFFFFu));
    const int c1 = __popc((unsigned int)((bits_all >> 16) & 0xFFFFu));
    const int c2 = __popc((unsigned int)((bits_all >> 32) & 0xFFFFu));
    const int c3 = __popc((unsigned int)((bits_all >> 48) & 0xFFFFu));

    const int q   = lane >> 4;       // quarter: owns slots q, q+4, q+8, q+12
    const int c16 = lane & 15;

    if constexpr (USE_BF16) {
        // ---- bf16 gather: quarter-wave per row, 4 paths in parallel, UNCONDITIONAL loads
        // (pad slots hit the zero row: one L1-hot line, adds 0.0). 2-stage register
        // pipeline keeps 8 loads in flight. No per-thread arrays -> spill-proof.
        const uint4* __restrict__ entb = (const uint4*)entbf;
        float4 l0 = {0,0,0,0}, h0 = l0, l1 = l0, h1 = l0, l2 = l0, h2 = l0, l3 = l0, h3 = l0;

        uint4 r0 = entb[(size_t)comp[wave][0][q] * 16 + c16];
        uint4 r1 = entb[(size_t)comp[wave][1][q] * 16 + c16];
        uint4 r2 = entb[(size_t)comp[wave][2][q] * 16 + c16];
        uint4 r3 = entb[(size_t)comp[wave][3][q] * 16 + c16];
        #pragma unroll
        for (int u = 0; u < 4; ++u) {
            uint4 n0, n1, n2, n3;
            if (u < 3) {
                const int slot = q + 4 * (u + 1);
                n0 = entb[(size_t)comp[wave][0][slot] * 16 + c16];
                n1 = entb[(size_t)comp[wave][1][slot] * 16 + c16];
                n2 = entb[(size_t)comp[wave][2][slot] * 16 + c16];
                n3 = entb[(size_t)comp[wave][3][slot] * 16 + c16];
            }
            acc_row(l0, h0, r0);
            acc_row(l1, h1, r1);
            acc_row(l2, h2, r2);
            acc_row(l3, h3, r3);
            if (u < 3) { r0 = n0; r1 = n1; r2 = n2; r3 = n3; }
        }
        // merge the 4 quarters (xor 16 then 32) -> every lane holds full sums
        merge_quarters(l0); merge_quarters(h0); merge_quarters(l1); merge_quarters(h1);
        merge_quarters(l2); merge_quarters(h2); merge_quarters(l3); merge_quarters(h3);

        // quarter q stores path q (all 64 lanes active)
        const int   cq   = (q == 0) ? c0 : (q == 1) ? c1 : (q == 2) ? c2 : c3;
        const float invq = 1.0f / (float)(cq > 1 ? cq : 1);
        float4 lo = (q == 0) ? l0 : (q == 1) ? l1 : (q == 2) ? l2 : l3;
        float4 hi = (q == 0) ? h0 : (q == 1) ? h1 : (q == 2) ? h2 : h3;
        lo.x *= invq; lo.y *= invq; lo.z *= invq; lo.w *= invq;
        hi.x *= invq; hi.y *= invq; hi.z *= invq; hi.w *= invq;
        const int pw = wave * 4 + q;
        *(float4*)&aggf[pw][c16 * 8]     = lo;
        *(float4*)&aggf[pw][c16 * 8 + 4] = hi;
        union { __bf16 h[8]; uint4 u4; } pk;
        pk.h[0] = (__bf16)lo.x; pk.h[1] = (__bf16)lo.y; pk.h[2] = (__bf16)lo.z; pk.h[3] = (__bf16)lo.w;
        pk.h[4] = (__bf16)hi.x; pk.h[5] = (__bf16)hi.y; pk.h[6] = (__bf16)hi.z; pk.h[7] = (__bf16)hi.w;
        *(uint4*)&aggbf[pw][c16 * 8] = pk.u4;
    } else {
        // ---- fp32 fallback (round-4 structure, known spill-free) ----
        const int half = lane >> 5;
        const int col  = lane & 31;
        const float4* __restrict__ entc = (const float4*)ent + col;
        float4 acc0 = {0.f,0.f,0.f,0.f}, acc1 = acc0, acc2 = acc0, acc3 = acc0;
        #pragma unroll
        for (int u = 0; u < 8; ++u) {
            const int slot = 2 * u + half;
            const int id0 = comp[wave][0][slot];
            const int id1 = comp[wave][1][slot];
            const int id2 = comp[wave][2][slot];
            const int id3 = comp[wave][3][slot];
            if (slot < c0) { float4 v = entc[(size_t)id0 << 5]; acc0.x += v.x; acc0.y += v.y; acc0.z += v.z; acc0.w += v.w; }
            if (slot < c1) { float4 v = entc[(size_t)id1 << 5]; acc1.x += v.x; acc1.y += v.y; acc1.z += v.z; acc1.w += v.w; }
            if (slot < c2) { float4 v = entc[(size_t)id2 << 5]; acc2.x += v.x; acc2.y += v.y; acc2.z += v.z; acc2.w += v.w; }
            if (slot < c3) { float4 v = entc[(size_t)id3 << 5]; acc3.x += v.x; acc3.y += v.y; acc3.z += v.z; acc3.w += v.w; }
        }
        #pragma unroll
        for (int i = 0; i < 4; ++i) {
            float4 a = (i == 0) ? acc0 : (i == 1) ? acc1 : (i == 2) ? acc2 : acc3;
            const int cnt = (i == 0) ? c0 : (i == 1) ? c1 : (i == 2) ? c2 : c3;
            a.x += __shfl_xor(a.x, 32); a.y += __shfl_xor(a.y, 32);
            a.z += __shfl_xor(a.z, 32); a.w += __shfl_xor(a.w, 32);
            const float inv = 1.0f / (float)(cnt > 1 ? cnt : 1);
            a.x *= inv; a.y *= inv; a.z *= inv; a.w *= inv;
            if (half == 0) {
                const int p = wave * 4 + i;
                *(float4*)&aggf[p][col * 4] = a;
                union { __bf16 h[4]; uint2 u2; } pk;
                pk.h[0] = (__bf16)a.x; pk.h[1] = (__bf16)a.y;
                pk.h[2] = (__bf16)a.z; pk.h[3] = (__bf16)a.w;
                *(uint2*)&aggbf[p][col * 4] = pk.u2;
            }
        }
    }
    __syncthreads();

    if (wave != 0) return;

    // ---- MLP for all 16 paths via MFMA (wave 0) ----
    const int m    = lane & 15;
    const int quad = lane >> 4;

    bf16x8_t afr[4];
    #pragma unroll
    for (int st = 0; st < 4; ++st)
        afr[st] = *(const bf16x8_t*)&aggbf[m][st * 32 + quad * 8];

    float xp[4] = {0.f, 0.f, 0.f, 0.f};
    #pragma unroll
    for (int t = 0; t < 4; ++t) {
        const int n = t * 16 + m;
        const float b1v = b1[n];
        f32x4_t acc = {b1v, b1v, b1v, b1v};
        const __bf16* bp = w1t + n * D_DIM + quad * 8;
        #pragma unroll
        for (int st = 0; st < 4; ++st) {
            bf16x8_t bfr = *(const bf16x8_t*)(bp + st * 32);
            acc = __builtin_amdgcn_mfma_f32_16x16x32_bf16(afr[st], bfr, acc, 0, 0, 0);
        }
        const float w2v = W2[n];
        #pragma unroll
        for (int r = 0; r < 4; ++r) {
            float h = acc[r] > 0.f ? acc[r] : 0.f;
            xp[r] += h * w2v;
        }
    }
    #pragma unroll
    for (int off = 1; off < 16; off <<= 1) {
        #pragma unroll
        for (int r = 0; r < 4; ++r) xp[r] += __shfl_xor(xp[r], off);
    }

    int myc[4]; int localv = 0;
    #pragma unroll
    for (int r = 0; r < 4; ++r) { myc[r] = cnts[quad * 4 + r]; localv += (myc[r] > 0); }
    int nv = localv + __shfl_xor(localv, 16);
    nv += __shfl_xor(nv, 32);
    const float invnv = 1.0f / (float)(nv > 1 ? nv : 1);
    const float b2v = b2[0];

    float wv[4];
    #pragma unroll
    for (int r = 0; r < 4; ++r) {
        float x = xp[r] + b2v;
        float w = 1.0f / (1.0f + __expf(-x));
        wv[r] = (myc[r] > 0) ? w * invnv : 0.f;
    }

    float fx = 0.f, fy = 0.f;
    #pragma unroll
    for (int p = 0; p < P_PATHS; ++p) {
        float wp = __shfl(wv[p & 3], (p >> 2) << 4);
        float2 a = *(const float2*)&aggf[p][2 * lane];
        fx += wp * a.x; fy += wp * a.y;
    }
    const int row = sids[s];
    *(float2*)&out[(size_t)row * D_DIM + 2 * lane] = make_float2(fx, fy);
}

extern "C" void kernel_launch(void* const* d_in, const int* in_sizes, int n_in,
                              void* d_out, int out_size, void* d_ws, size_t ws_size,
                              hipStream_t stream)
{
    const float* ent  = (const float*)d_in[0];
    const float* W1   = (const float*)d_in[1];
    const float* b1   = (const float*)d_in[2];
    const float* W2   = (const float*)d_in[3];
    const float* b2   = (const float*)d_in[4];
    const int*   sids = (const int*)d_in[5];
    const int*   eids = (const int*)d_in[6];
    const void*  emsk = (const void*)d_in[7];
    float* out = (float*)d_out;

    const int ND   = in_sizes[0];                     // N*D elements of entity table
    const int nent = ND / D_DIM;                      // N (pad row index)
    __bf16* w1t_ws = (__bf16*)d_ws;                   // 16 KB
    __bf16* entbf  = (__bf16*)((char*)d_ws + 16384);  // 2*(ND + D) bytes (incl. pad row)
    const bool useBf16 = (ws_size >= 16384 + ((size_t)ND + D_DIM) * 2)
                         && ((ND & 3) == 0) && ((out_size & 3) == 0);

    if (useBf16) {
        const int n4 = ND >> 2, o4 = out_size >> 2;
        const int mx = n4 > o4 ? n4 : o4;
        prep_fused_kernel<<<(mx + 255) / 256, 256, 0, stream>>>(ent, W1, entbf, w1t_ws,
                                                                (float4*)out, n4, o4);
        PathGuidedAggregator_kernel<true><<<S_NODES, 256, 0, stream>>>(
            ent, (const __bf16*)entbf, b1, W2, b2, sids, eids, emsk,
            (const __bf16*)w1t_ws, out, nent);
    } else {
        hipMemsetAsync(d_out, 0, (size_t)out_size * sizeof(float), stream);
        prep_w1_kernel<<<32, 256, 0, stream>>>(W1, w1t_ws);
        PathGuidedAggregator_kernel<false><<<S_NODES, 256, 0, stream>>>(
            ent, (const __bf16*)entbf, b1, W2, b2, sids, eids, emsk,
            (const __bf16*)w1t_ws, out, nent);
    }
}